// Round 6
// baseline (110.803 us; speedup 1.0000x reference)
//
#include <hip/hip_runtime.h>
#include <math.h>

#define D 256            // feature dim (D_IN == D_OUT == 256)
#define MAXNORM (1.0f - 4e-3f)   // (1 - BALL_EPS)/sqrt(c), c = 1
#define MIN_NORM 1e-15f

typedef _Float16 v8h __attribute__((ext_vector_type(8)));
typedef _Float16 h4  __attribute__((ext_vector_type(4)));
typedef float    v4f __attribute__((ext_vector_type(4)));

__device__ __forceinline__ float wave_reduce_sum(float v) {
    #pragma unroll
    for (int m = 32; m >= 1; m >>= 1) v += __shfl_xor(v, m, 64);
    return v;
}

__device__ __forceinline__ float dot4(const float4& a, const float4& b) {
    return a.x * b.x + a.y * b.y + a.z * b.z + a.w * b.w;
}

__device__ __forceinline__ float artanh_clip(float x) {
    x = fminf(fmaxf(x, -1.0f + 1e-7f), 1.0f - 1e-7f);
    return 0.5f * (log1pf(x) - log1pf(-x));
}

// ---------------------------------------------------------------------------
// Kernel 1 (prep): fuses
//   (a) rowptr fill from sorted adj_row          [all blocks, e < E]
//   (b) W fp32 -> fp16 cast                      [blocks 0..63]
//   (c) hyp_bias = proj(expmap0(bias)) + ||.||^2 [block 64, wave 0]
// NOTE (R5 post-mortem): keep this a SEPARATE kernel. Folding the rowptr fill
// into the MFMA kernel coincided with a replay-divergence failure + 20us
// regression. Pre-casting Wh here also keeps ~256 v_cvt/thread out of the
// MFMA hot loop.
// ---------------------------------------------------------------------------
__global__ __launch_bounds__(256) void prep_kernel(
    const float* __restrict__ bias, const float* __restrict__ W,
    const int* __restrict__ rows,
    float* __restrict__ HB, _Float16* __restrict__ Wh,
    int* __restrict__ rowptr, int N, int E)
{
    const int b = blockIdx.x, t = threadIdx.x;
    const int e = b * 256 + t;

    if (e < E) {
        int r1 = rows[e];
        if (e == 0) {
            for (int r = 0; r <= r1; ++r) rowptr[r] = 0;
        } else {
            int r0 = rows[e - 1];
            for (int r = r0 + 1; r <= r1; ++r) rowptr[r] = e;
        }
        if (e == E - 1) {
            for (int r = r1 + 1; r <= N; ++r) rowptr[r] = E;
        }
    }

    if (b < 64) {   // W cast: 64 blocks x 256 threads x float4 = 65536 floats
        int i = b * 256 + t;
        float4 v = ((const float4*)W)[i];
        h4 o; o[0] = (_Float16)v.x; o[1] = (_Float16)v.y;
        o[2] = (_Float16)v.z; o[3] = (_Float16)v.w;
        *(h4*)(Wh + 4 * (size_t)i) = o;
    }

    if (b == 64 && t < 64) {   // bias (single wave)
        int l = t;
        float4 v = *(const float4*)(bias + 4 * l);
        float bn = fmaxf(sqrtf(wave_reduce_sum(dot4(v, v))), MIN_NORM);
        float f = tanhf(bn) / bn;
        float4 h = make_float4(v.x * f, v.y * f, v.z * f, v.w * f);
        float hn = fmaxf(sqrtf(wave_reduce_sum(dot4(h, h))), MIN_NORM);
        float s = (hn > MAXNORM) ? (MAXNORM / hn) : 1.0f;
        h.x *= s; h.y *= s; h.z *= s; h.w *= s;
        *(float4*)(HB + 4 * l) = h;
        float y2 = wave_reduce_sum(dot4(h, h));
        if (l == 0) HB[D] = y2;
    }
}

// ---------------------------------------------------------------------------
// Kernel 2 (fused GEMM + rowops): XT = rowops(X @ W^T) in one pass.
// HypLinear tail collapses to xt[row][col] = A[row]*mx[row][col] + B[row]*y[col]
// with A,B from three per-row scalars: ||x||^2, ||mx||^2, <mx,y>.
// mx never leaves registers.
// Block: 256 threads (4 waves), 16 rows x 256 cols; wave w = cols [64w,64w+64).
// Frag layouts (verified m89/m120): A[m=lane&15][k=quad*8+j],
// B[k=quad*8+j][n=lane&15] (Wh[col][k..k+7] contiguous), C: col=lane&15,
// row=quad*4+reg.
// ---------------------------------------------------------------------------
#define AS16 264   // LDS row stride in halves (+8 pad)

__global__ __launch_bounds__(256) void gemmrow_kernel(
    const float* __restrict__ X, const _Float16* __restrict__ Wh,
    const float* __restrict__ HB, _Float16* __restrict__ XT, int N)
{
    __shared__ _Float16 As[16 * AS16];
    __shared__ float xnsq[16];
    __shared__ float part_s[16][4];
    __shared__ float part_d[16][4];
    __shared__ float Arow[16], Brow[16];

    const int t = threadIdx.x;
    const int r0 = blockIdx.x * 16;

    // ---- stage X rows [r0, r0+16) as fp16; per-row ||x||^2 in fp32 ----
    {
        const int r = t >> 4, q2 = t & 15;
        const int grow = r0 + r;
        float ss = 0.0f;
        #pragma unroll
        for (int j = 0; j < 4; ++j) {
            const int fi = q2 + j * 16;
            float4 v = make_float4(0.f, 0.f, 0.f, 0.f);
            if (grow < N) v = ((const float4*)X)[(size_t)grow * 64 + fi];
            ss += dot4(v, v);
            h4 hv; hv[0] = (_Float16)v.x; hv[1] = (_Float16)v.y;
            hv[2] = (_Float16)v.z; hv[3] = (_Float16)v.w;
            *(h4*)&As[r * AS16 + fi * 4] = hv;
        }
        ss += __shfl_xor(ss, 1, 64);
        ss += __shfl_xor(ss, 2, 64);
        ss += __shfl_xor(ss, 4, 64);
        ss += __shfl_xor(ss, 8, 64);
        if (q2 == 0) xnsq[r] = ss;
    }
    __syncthreads();

    // ---- MFMA: wave w computes rows 0..15 x cols [64w, 64w+64) ----
    const int w  = t >> 6;
    const int l  = t & 63;
    const int lm = l & 15;
    const int q  = l >> 4;

    v4f acc[4];
    #pragma unroll
    for (int ct = 0; ct < 4; ++ct)
        #pragma unroll
        for (int i = 0; i < 4; ++i) acc[ct][i] = 0.0f;

    const _Float16* WhB = Wh + (size_t)(64 * w + lm) * 256 + q * 8;

    #pragma unroll
    for (int kc = 0; kc < 8; ++kc) {
        v8h a = *(const v8h*)&As[lm * AS16 + kc * 32 + q * 8];
        #pragma unroll
        for (int ct = 0; ct < 4; ++ct) {
            v8h bfr = *(const v8h*)(WhB + (size_t)ct * 16 * 256 + kc * 32);
            acc[ct] = __builtin_amdgcn_mfma_f32_16x16x32_f16(a, bfr, acc[ct], 0, 0, 0);
        }
    }

    // y values for this lane's 4 columns
    float yv[4];
    #pragma unroll
    for (int ct = 0; ct < 4; ++ct) yv[ct] = HB[64 * w + ct * 16 + lm];

    // ---- per-row reductions: s = sum mx^2, d = <mx, y> ----
    {
        float s_[4], d_[4];
        #pragma unroll
        for (int i = 0; i < 4; ++i) {
            float s = 0.f, d = 0.f;
            #pragma unroll
            for (int ct = 0; ct < 4; ++ct) {
                float v = acc[ct][i];
                s = fmaf(v, v, s);
                d = fmaf(v, yv[ct], d);
            }
            #pragma unroll
            for (int m = 1; m <= 8; m <<= 1) {
                s += __shfl_xor(s, m, 64);
                d += __shfl_xor(d, m, 64);
            }
            s_[i] = s; d_[i] = d;
        }
        if (lm == 0) {
            #pragma unroll
            for (int i = 0; i < 4; ++i) {
                part_s[q * 4 + i][w] = s_[i];
                part_d[q * 4 + i][w] = d_[i];
            }
        }
    }
    __syncthreads();

    // ---- per-row scalar chain (exact rowops algebra, fp32) ----
    if (t < 16) {
        float mx2 = part_s[t][0] + part_s[t][1] + part_s[t][2] + part_s[t][3];
        float mxy = part_d[t][0] + part_d[t][1] + part_d[t][2] + part_d[t][3];
        float y2  = HB[D];
        float xn  = fmaxf(sqrtf(xnsq[t]), MIN_NORM);
        float mxn = fmaxf(sqrtf(mx2), MIN_NORM);
        float r  = (mxn / xn) * artanh_clip(xn);
        float th = tanhf(r);              // ||h|| before proj
        float f  = th / mxn;
        float hn = fmaxf(th, MIN_NORM);
        float s  = (hn > MAXNORM) ? (MAXNORM / hn) : 1.0f;
        float fs = f * s;                 // h = fs * mx
        float x2 = th * th * s * s;
        float xy  = fs * mxy;
        float ch  = 1.0f + 2.0f * xy + y2;
        float cy  = 1.0f - x2;
        float inv = 1.0f / fmaxf(1.0f + 2.0f * xy + x2 * y2, MIN_NORM);
        float alpha = ch * fs * inv;      // g = alpha*mx + beta*y
        float beta  = cy * inv;
        float gss = alpha * alpha * mx2 + 2.0f * alpha * beta * mxy + beta * beta * y2;
        float gn  = fmaxf(sqrtf(gss), MIN_NORM);
        float s2  = (gn > MAXNORM) ? (MAXNORM / gn) : 1.0f;
        float pn  = fmaxf(gn * s2, MIN_NORM);
        float lf  = artanh_clip(pn) / pn;
        Arow[t] = lf * s2 * alpha;
        Brow[t] = lf * s2 * beta;
    }
    __syncthreads();

    // ---- write XT = A*mx + B*y as fp16, straight from fragments ----
    #pragma unroll
    for (int i = 0; i < 4; ++i) {
        const int rr = q * 4 + i;
        const int row = r0 + rr;
        if (row < N) {
            float A = Arow[rr], B = Brow[rr];
            #pragma unroll
            for (int ct = 0; ct < 4; ++ct) {
                float v = fmaf(A, acc[ct][i], B * yv[ct]);
                XT[(size_t)row * 256 + 64 * w + ct * 16 + lm] = (_Float16)v;
            }
        }
    }
}

// ---------------------------------------------------------------------------
// Kernel 3: sparse aggregation (fp16 gather, fp32 accum) + HypAct
// One wave per node (R4-proven structure); shfl-broadcast cols/vals.
// R6 change: gather pipeline depth 8 -> 16 (8 KB in flight per wave instead
// of 4 KB — the gather is latency-bound, not BW-bound). Edge accumulation
// order unchanged -> bitwise-identical output vs R4.
// ---------------------------------------------------------------------------
__global__ __launch_bounds__(256) void agg_kernel(
    const int* __restrict__ rowptr, const int* __restrict__ cols,
    const float* __restrict__ vals, const _Float16* __restrict__ XT,
    float* __restrict__ OUT, int N)
{
    int node = (int)((blockIdx.x * (size_t)blockDim.x + threadIdx.x) >> 6);
    int l = threadIdx.x & 63;
    if (node >= N) return;

    int start = rowptr[node];
    int end   = rowptr[node + 1];

    const h4* xt4 = (const h4*)XT;
    float4 acc = make_float4(0.f, 0.f, 0.f, 0.f);

    for (int base = start; base < end; base += 64) {
        int idx = base + l;
        bool ok = idx < end;
        int   myc = ok ? cols[idx] : 0;
        float myv = ok ? vals[idx] : 0.0f;
        int cnt = min(64, end - base);
        int cnt16 = (cnt + 15) & ~15;   // pad to 16; padded lanes v=0, c=0

        for (int j = 0; j < cnt16; j += 16) {
            int   c[16];
            float v[16];
            #pragma unroll
            for (int u = 0; u < 16; ++u) {
                c[u] = __shfl(myc, j + u, 64);
                v[u] = __shfl(myv, j + u, 64);
            }
            h4 m[16];
            #pragma unroll
            for (int u = 0; u < 16; ++u)
                m[u] = xt4[(size_t)c[u] * 64 + l];
            #pragma unroll
            for (int u = 0; u < 16; ++u) {
                acc.x = fmaf(v[u], (float)m[u][0], acc.x);
                acc.y = fmaf(v[u], (float)m[u][1], acc.y);
                acc.z = fmaf(v[u], (float)m[u][2], acc.z);
                acc.w = fmaf(v[u], (float)m[u][3], acc.w);
            }
        }
    }

    // expmap0
    float un = fmaxf(sqrtf(wave_reduce_sum(dot4(acc, acc))), MIN_NORM);
    float f = tanhf(un) / un;
    float4 h = make_float4(acc.x * f, acc.y * f, acc.z * f, acc.w * f);
    // proj
    float hn = fmaxf(sqrtf(wave_reduce_sum(dot4(h, h))), MIN_NORM);
    float s = (hn > MAXNORM) ? (MAXNORM / hn) : 1.0f;
    h.x *= s; h.y *= s; h.z *= s; h.w *= s;
    // logmap0 + relu
    float pn = fmaxf(hn * s, MIN_NORM);
    float lf = artanh_clip(pn) / pn;
    float4 tt = make_float4(fmaxf(h.x * lf, 0.f), fmaxf(h.y * lf, 0.f),
                            fmaxf(h.z * lf, 0.f), fmaxf(h.w * lf, 0.f));
    // expmap0 (c_out = 1)
    float un2 = fmaxf(sqrtf(wave_reduce_sum(dot4(tt, tt))), MIN_NORM);
    float f2 = tanhf(un2) / un2;
    float4 o = make_float4(tt.x * f2, tt.y * f2, tt.z * f2, tt.w * f2);
    // proj
    float on = fmaxf(sqrtf(wave_reduce_sum(dot4(o, o))), MIN_NORM);
    float s2 = (on > MAXNORM) ? (MAXNORM / on) : 1.0f;
    o.x *= s2; o.y *= s2; o.z *= s2; o.w *= s2;

    *(float4*)(OUT + (size_t)node * D + 4 * l) = o;
}

// ---------------------------------------------------------------------------
extern "C" void kernel_launch(void* const* d_in, const int* in_sizes, int n_in,
                              void* d_out, int out_size, void* d_ws, size_t ws_size,
                              hipStream_t stream) {
    const float* X    = (const float*)d_in[0];
    const float* W    = (const float*)d_in[1];
    const float* bias = (const float*)d_in[2];
    const float* vals = (const float*)d_in[3];
    const int*   rows = (const int*)d_in[4];
    const int*   cols = (const int*)d_in[5];
    float* OUT = (float*)d_out;

    const int N = in_sizes[0] / D;   // 10000
    const int E = in_sizes[3];       // 320000

    // ws layout (float units): rowptr [10240] | HB [512] | Wh [32768] | XT [...]
    int*      rowptr = (int*)d_ws;
    float*    HB = (float*)d_ws + 10240;
    _Float16* Wh = (_Float16*)((float*)d_ws + 10240 + 512);
    _Float16* XT = (_Float16*)((float*)d_ws + 10240 + 512 + 32768);

    prep_kernel<<<(E + 255) / 256, 256, 0, stream>>>(bias, W, rows, HB, Wh, rowptr, N, E);
    gemmrow_kernel<<<(N + 15) / 16, 256, 0, stream>>>(X, Wh, HB, XT, N);
    int wave_blocks = (N + 3) / 4;   // 4 waves per 256-thread block
    agg_kernel<<<wave_blocks, 256, 0, stream>>>(rowptr, cols, vals, XT, OUT, N);
}